// Round 19
// baseline (497.049 us; speedup 1.0000x reference)
//
#include <hip/hip_runtime.h>

typedef unsigned short ushort_t;
typedef unsigned int uint_t;
typedef __bf16 bf16_t;
typedef __bf16 bf16x8 __attribute__((ext_vector_type(8)));
typedef float f32x4 __attribute__((ext_vector_type(4)));

// ---------- helpers ----------
__device__ __forceinline__ float b2f(ushort_t u) {
    union { uint_t i; float f; } v; v.i = ((uint_t)u) << 16; return v.f;
}
__device__ __forceinline__ ushort_t f2b(float f) {
    union { float f; uint_t i; } v; v.f = f;
    uint_t r = v.i + 0x7fffu + ((v.i >> 16) & 1u);
    return (ushort_t)(r >> 16);
}
__device__ __forceinline__ float gelu_exact(float x) {
    return 0.5f * x * (1.0f + erff(x * 0.70710678118654752f));
}

// ---------- all weight conversions in ONE launch ----------
__global__ void prep_weights(const float* __restrict__ q_w, const float* __restrict__ sr2_w,
                             const float* __restrict__ kv1_w, const float* __restrict__ kv2_w,
                             const float* __restrict__ proj_w, const float* __restrict__ fc1_w,
                             const float* __restrict__ fc2_w, const float* __restrict__ sr1_w,
                             ushort_t* __restrict__ dst) {
    int gid = blockIdx.x * 256 + threadIdx.x;
    int i = gid;
    if (i < 147456) { dst[gid] = f2b(q_w[i]); return; }
    i -= 147456;
    if (i < 147456) { dst[gid] = f2b(sr2_w[i]); return; }
    i -= 147456;
    if (i < 147456) { dst[gid] = f2b(kv1_w[i]); return; }
    i -= 147456;
    if (i < 147456) { dst[gid] = f2b(kv2_w[i]); return; }
    i -= 147456;
    if (i < 147456) { dst[gid] = f2b(proj_w[i]); return; }
    i -= 147456;
    if (i < 589824) { dst[gid] = f2b(fc1_w[i]); return; }
    i -= 589824;
    if (i < 589824) { dst[gid] = f2b(fc2_w[i]); return; }
    i -= 589824;
    if (i < 1179648) {
        int co = i / 3072, r = i % 3072, kk = r / 384, ci = r % 384;
        dst[gid] = f2b(sr1_w[((size_t)co * 384 + ci) * 8 + kk]);
    }
}

// ---------- im2col for sr1 ----------
__global__ void im2col_kernel(const ushort_t* __restrict__ xa, ushort_t* __restrict__ A1) {
    int gid = blockIdx.x * 256 + threadIdx.x;
    if (gid >= 1024 * 3072) return;
    int m = gid / 3072, r = gid % 3072, kk = r / 384, ci = r % 384;
    int b = m >> 9, n1 = m & 511;
    int ho = n1 >> 6, wo = (n1 >> 3) & 7, dz = n1 & 7;
    int n = ((2 * ho + ((kk >> 2) & 1)) << 8) + ((2 * wo + ((kk >> 1) & 1)) << 4) + (2 * dz + (kk & 1));
    A1[gid] = xa[((size_t)b * 4096 + n) * 384 + ci];
}

// ---------- LayerNorm (+ optional GELU); C = 384 ----------
__global__ __launch_bounds__(128) void ln_kernel(const float* __restrict__ in,
                                                 const float* __restrict__ w,
                                                 const float* __restrict__ b,
                                                 float* __restrict__ outf,
                                                 ushort_t* __restrict__ outb, int act) {
    const int C = 384;
    int row = blockIdx.x, tid = threadIdx.x;
    size_t base = (size_t)row * C;
    float x[3], s = 0.f, s2 = 0.f;
#pragma unroll
    for (int i = 0; i < 3; i++) {
        int c = tid + i * 128;
        float v = in[base + c];
        x[i] = v; s += v; s2 += v * v;
    }
    for (int off = 32; off; off >>= 1) { s += __shfl_down(s, off); s2 += __shfl_down(s2, off); }
    __shared__ float sc[4];
    int lane = tid & 63, wid = tid >> 6;
    if (lane == 0) { sc[wid] = s; sc[wid + 2] = s2; }
    __syncthreads();
    float ts = sc[0] + sc[1], ts2 = sc[2] + sc[3];
    float mean = ts / C;
    float var = ts2 / C - mean * mean;
    float rstd = rsqrtf(var + 1e-5f);
#pragma unroll
    for (int i = 0; i < 3; i++) {
        int c = tid + i * 128;
        float v = (x[i] - mean) * rstd * w[c] + b[c];
        if (act) v = gelu_exact(v);
        if (outf) outf[base + c] = v;
        if (outb) outb[base + c] = f2b(v);
    }
}

// ---------- LN over sum of 4 split-K partials + conv bias, then GELU -> bf16 ----------
__global__ __launch_bounds__(128) void ln4_kernel(const float* __restrict__ p,
                                                  const float* __restrict__ cbias,
                                                  const float* __restrict__ w,
                                                  const float* __restrict__ b,
                                                  ushort_t* __restrict__ outb) {
    const int C = 384;
    const size_t CH = (size_t)1024 * 384;
    int row = blockIdx.x, tid = threadIdx.x;
    size_t base = (size_t)row * C;
    float x[3], s = 0.f, s2 = 0.f;
#pragma unroll
    for (int i = 0; i < 3; i++) {
        int c = tid + i * 128;
        float v = ((p[base + c] + p[CH + base + c]) + (p[2 * CH + base + c] + p[3 * CH + base + c]))
                  + cbias[c];
        x[i] = v; s += v; s2 += v * v;
    }
    for (int off = 32; off; off >>= 1) { s += __shfl_down(s, off); s2 += __shfl_down(s2, off); }
    __shared__ float sc[4];
    int lane = tid & 63, wid = tid >> 6;
    if (lane == 0) { sc[wid] = s; sc[wid + 2] = s2; }
    __syncthreads();
    float ts = sc[0] + sc[1], ts2 = sc[2] + sc[3];
    float mean = ts / C;
    float var = ts2 / C - mean * mean;
    float rstd = rsqrtf(var + 1e-5f);
#pragma unroll
    for (int i = 0; i < 3; i++) {
        int c = tid + i * 128;
        float v = (x[i] - mean) * rstd * w[c] + b[c];
        outb[base + c] = f2b(gelu_exact(v));
    }
}

// ---------- MFMA GEMM 128x128, BK=32, reg-prefetch (used for fc1) ----------
__global__ __launch_bounds__(256) void mfma_gemm(const ushort_t* __restrict__ A,
                                                 const ushort_t* __restrict__ W,
                                                 const float* __restrict__ bias,
                                                 const float* __restrict__ res,
                                                 float* __restrict__ outf,
                                                 ushort_t* __restrict__ outb,
                                                 int M, int N, int K, int act) {
    __shared__ bf16_t Asl[128][40];
    __shared__ bf16_t Wsl[128][40];
    int tid = threadIdx.x;
    int wave = tid >> 6, lane = tid & 63, g = lane >> 4, c = lane & 15;
    int wm = wave >> 1, wn = wave & 1;
    int m0 = blockIdx.y * 128, n0 = blockIdx.x * 128;
    int srow = tid >> 1, sseg = tid & 1;
    const ushort_t* Abase = A + (size_t)(m0 + srow) * K + sseg * 16;
    const ushort_t* Wbase = W + (size_t)(n0 + srow) * K + sseg * 16;

    f32x4 acc[4][4];
#pragma unroll
    for (int i = 0; i < 4; i++)
#pragma unroll
        for (int j = 0; j < 4; j++) acc[i][j] = f32x4{0.f, 0.f, 0.f, 0.f};

    uint4 av0 = *(const uint4*)Abase, av1 = *(const uint4*)(Abase + 8);
    uint4 wv0 = *(const uint4*)Wbase, wv1 = *(const uint4*)(Wbase + 8);
    for (int k0 = 0; k0 < K; k0 += 32) {
        __syncthreads();
        *(uint4*)&Asl[srow][sseg * 16] = av0;
        *(uint4*)&Asl[srow][sseg * 16 + 8] = av1;
        *(uint4*)&Wsl[srow][sseg * 16] = wv0;
        *(uint4*)&Wsl[srow][sseg * 16 + 8] = wv1;
        __syncthreads();
        uint4 nav0, nav1, nwv0, nwv1;
        bool more = (k0 + 32 < K);
        if (more) {
            nav0 = *(const uint4*)(Abase + k0 + 32);
            nav1 = *(const uint4*)(Abase + k0 + 40);
            nwv0 = *(const uint4*)(Wbase + k0 + 32);
            nwv1 = *(const uint4*)(Wbase + k0 + 40);
        }
        bf16x8 af[4], bf[4];
#pragma unroll
        for (int fi = 0; fi < 4; fi++) af[fi] = *(bf16x8*)&Asl[wm * 64 + fi * 16 + c][g * 8];
#pragma unroll
        for (int fj = 0; fj < 4; fj++) bf[fj] = *(bf16x8*)&Wsl[wn * 64 + fj * 16 + c][g * 8];
#pragma unroll
        for (int fi = 0; fi < 4; fi++)
#pragma unroll
            for (int fj = 0; fj < 4; fj++)
                acc[fi][fj] = __builtin_amdgcn_mfma_f32_16x16x32_bf16(af[fi], bf[fj], acc[fi][fj], 0, 0, 0);
        if (more) { av0 = nav0; av1 = nav1; wv0 = nwv0; wv1 = nwv1; }
    }

#pragma unroll
    for (int fi = 0; fi < 4; fi++) {
#pragma unroll
        for (int fj = 0; fj < 4; fj++) {
            int n = n0 + wn * 64 + fj * 16 + c;
            float bv = bias ? bias[n] : 0.f;
#pragma unroll
            for (int i = 0; i < 4; i++) {
                int m = m0 + wm * 64 + fi * 16 + 4 * g + i;
                float v = acc[fi][fj][i] + bv;
                if (act == 1) v = gelu_exact(v);
                size_t idx = (size_t)m * N + n;
                if (res) v += res[idx];
                if (outf) outf[idx] = v;
                if (outb) outb[idx] = f2b(v);
            }
        }
    }
}

// ---------- MFMA GEMM 64x64, BK=64, reg-prefetch (+output scale) ----------
__global__ __launch_bounds__(256) void gemm64(const ushort_t* __restrict__ A,
                                              const ushort_t* __restrict__ W,
                                              const float* __restrict__ bias,
                                              const float* __restrict__ res,
                                              float* __restrict__ outf,
                                              ushort_t* __restrict__ outb,
                                              int M, int N, int K, int act, float oscale) {
    __shared__ bf16_t Asl[64][72];
    __shared__ bf16_t Wsl[64][72];
    int tid = threadIdx.x;
    int wave = tid >> 6, lane = tid & 63, g = lane >> 4, c = lane & 15;
    int wm = wave >> 1, wn = wave & 1;
    int m0 = blockIdx.y * 64, n0 = blockIdx.x * 64;
    int srow = tid >> 2, sseg = tid & 3;
    const ushort_t* Abase = A + (size_t)(m0 + srow) * K + sseg * 16;
    const ushort_t* Wbase = W + (size_t)(n0 + srow) * K + sseg * 16;

    f32x4 acc[2][2];
#pragma unroll
    for (int i = 0; i < 2; i++)
#pragma unroll
        for (int j = 0; j < 2; j++) acc[i][j] = f32x4{0.f, 0.f, 0.f, 0.f};

    uint4 av0 = *(const uint4*)Abase, av1 = *(const uint4*)(Abase + 8);
    uint4 wv0 = *(const uint4*)Wbase, wv1 = *(const uint4*)(Wbase + 8);
    for (int k0 = 0; k0 < K; k0 += 64) {
        __syncthreads();
        *(uint4*)&Asl[srow][sseg * 16] = av0;
        *(uint4*)&Asl[srow][sseg * 16 + 8] = av1;
        *(uint4*)&Wsl[srow][sseg * 16] = wv0;
        *(uint4*)&Wsl[srow][sseg * 16 + 8] = wv1;
        __syncthreads();
        uint4 nav0, nav1, nwv0, nwv1;
        bool more = (k0 + 64 < K);
        if (more) {
            nav0 = *(const uint4*)(Abase + k0 + 64);
            nav1 = *(const uint4*)(Abase + k0 + 72);
            nwv0 = *(const uint4*)(Wbase + k0 + 64);
            nwv1 = *(const uint4*)(Wbase + k0 + 72);
        }
#pragma unroll
        for (int kk = 0; kk < 2; kk++) {
            bf16x8 af[2], bf[2];
#pragma unroll
            for (int fi = 0; fi < 2; fi++) af[fi] = *(bf16x8*)&Asl[wm * 32 + fi * 16 + c][kk * 32 + g * 8];
#pragma unroll
            for (int fj = 0; fj < 2; fj++) bf[fj] = *(bf16x8*)&Wsl[wn * 32 + fj * 16 + c][kk * 32 + g * 8];
#pragma unroll
            for (int fi = 0; fi < 2; fi++)
#pragma unroll
                for (int fj = 0; fj < 2; fj++)
                    acc[fi][fj] = __builtin_amdgcn_mfma_f32_16x16x32_bf16(af[fi], bf[fj], acc[fi][fj], 0, 0, 0);
        }
        if (more) { av0 = nav0; av1 = nav1; wv0 = nwv0; wv1 = nwv1; }
    }

#pragma unroll
    for (int fi = 0; fi < 2; fi++) {
#pragma unroll
        for (int fj = 0; fj < 2; fj++) {
            int n = n0 + wn * 32 + fj * 16 + c;
            float bv = bias ? bias[n] : 0.f;
#pragma unroll
            for (int i = 0; i < 4; i++) {
                int m = m0 + wm * 32 + fi * 16 + 4 * g + i;
                float v = (acc[fi][fj][i] + bv) * oscale;
                if (act == 1) v = gelu_exact(v);
                size_t idx = (size_t)m * N + n;
                if (res) v += res[idx];
                if (outf) outf[idx] = v;
                if (outb) outb[idx] = f2b(v);
            }
        }
    }
}

// ---------- split-K GEMM for sr1: K=3072 in 4 chunks of 768; f32 partials ----------
__global__ __launch_bounds__(256) void gemm64sk(const ushort_t* __restrict__ A,
                                                const ushort_t* __restrict__ W,
                                                float* __restrict__ yp) {
    const int K = 3072, N = 384, KC = 768;
    __shared__ bf16_t Asl[64][72];
    __shared__ bf16_t Wsl[64][72];
    int tid = threadIdx.x;
    int wave = tid >> 6, lane = tid & 63, g = lane >> 4, c = lane & 15;
    int wm = wave >> 1, wn = wave & 1;
    int m0 = blockIdx.y * 64, n0 = blockIdx.x * 64, kc = blockIdx.z;
    int kbeg = kc * KC;
    int srow = tid >> 2, sseg = tid & 3;
    const ushort_t* Abase = A + (size_t)(m0 + srow) * K + kbeg + sseg * 16;
    const ushort_t* Wbase = W + (size_t)(n0 + srow) * K + kbeg + sseg * 16;
    float* out = yp + (size_t)kc * 1024 * 384;

    f32x4 acc[2][2];
#pragma unroll
    for (int i = 0; i < 2; i++)
#pragma unroll
        for (int j = 0; j < 2; j++) acc[i][j] = f32x4{0.f, 0.f, 0.f, 0.f};

    uint4 av0 = *(const uint4*)Abase, av1 = *(const uint4*)(Abase + 8);
    uint4 wv0 = *(const uint4*)Wbase, wv1 = *(const uint4*)(Wbase + 8);
    for (int k0 = 0; k0 < KC; k0 += 64) {
        __syncthreads();
        *(uint4*)&Asl[srow][sseg * 16] = av0;
        *(uint4*)&Asl[srow][sseg * 16 + 8] = av1;
        *(uint4*)&Wsl[srow][sseg * 16] = wv0;
        *(uint4*)&Wsl[srow][sseg * 16 + 8] = wv1;
        __syncthreads();
        uint4 nav0, nav1, nwv0, nwv1;
        bool more = (k0 + 64 < KC);
        if (more) {
            nav0 = *(const uint4*)(Abase + k0 + 64);
            nav1 = *(const uint4*)(Abase + k0 + 72);
            nwv0 = *(const uint4*)(Wbase + k0 + 64);
            nwv1 = *(const uint4*)(Wbase + k0 + 72);
        }
#pragma unroll
        for (int kk = 0; kk < 2; kk++) {
            bf16x8 af[2], bf[2];
#pragma unroll
            for (int fi = 0; fi < 2; fi++) af[fi] = *(bf16x8*)&Asl[wm * 32 + fi * 16 + c][kk * 32 + g * 8];
#pragma unroll
            for (int fj = 0; fj < 2; fj++) bf[fj] = *(bf16x8*)&Wsl[wn * 32 + fj * 16 + c][kk * 32 + g * 8];
#pragma unroll
            for (int fi = 0; fi < 2; fi++)
#pragma unroll
                for (int fj = 0; fj < 2; fj++)
                    acc[fi][fj] = __builtin_amdgcn_mfma_f32_16x16x32_bf16(af[fi], bf[fj], acc[fi][fj], 0, 0, 0);
        }
        if (more) { av0 = nav0; av1 = nav1; wv0 = nwv0; wv1 = nwv1; }
    }

#pragma unroll
    for (int fi = 0; fi < 2; fi++) {
#pragma unroll
        for (int fj = 0; fj < 2; fj++) {
            int n = n0 + wn * 32 + fj * 16 + c;
#pragma unroll
            for (int i = 0; i < 4; i++) {
                int m = m0 + wm * 32 + fi * 16 + 4 * g + i;
                out[(size_t)m * N + n] = acc[fi][fj][i];
            }
        }
    }
}

// ---------- merged kv projections: y<128 -> kv2 (M=8192), else kv1 (M=1024) ----------
__global__ __launch_bounds__(256) void gemm_kv(const ushort_t* __restrict__ A2,
                                               const ushort_t* __restrict__ W2,
                                               ushort_t* __restrict__ O2,
                                               const ushort_t* __restrict__ A1,
                                               const ushort_t* __restrict__ W1,
                                               ushort_t* __restrict__ O1) {
    const int K = 384, N = 384;
    __shared__ bf16_t Asl[64][72];
    __shared__ bf16_t Wsl[64][72];
    int tid = threadIdx.x;
    int wave = tid >> 6, lane = tid & 63, g = lane >> 4, c = lane & 15;
    int wm = wave >> 1, wn = wave & 1;
    int by = blockIdx.y;
    const ushort_t* A; const ushort_t* W; ushort_t* O; int m0;
    if (by < 128) { A = A2; W = W2; O = O2; m0 = by * 64; }
    else          { A = A1; W = W1; O = O1; m0 = (by - 128) * 64; }
    int n0 = blockIdx.x * 64;
    int srow = tid >> 2, sseg = tid & 3;
    const ushort_t* Abase = A + (size_t)(m0 + srow) * K + sseg * 16;
    const ushort_t* Wbase = W + (size_t)(n0 + srow) * K + sseg * 16;

    f32x4 acc[2][2];
#pragma unroll
    for (int i = 0; i < 2; i++)
#pragma unroll
        for (int j = 0; j < 2; j++) acc[i][j] = f32x4{0.f, 0.f, 0.f, 0.f};

    uint4 av0 = *(const uint4*)Abase, av1 = *(const uint4*)(Abase + 8);
    uint4 wv0 = *(const uint4*)Wbase, wv1 = *(const uint4*)(Wbase + 8);
    for (int k0 = 0; k0 < K; k0 += 64) {
        __syncthreads();
        *(uint4*)&Asl[srow][sseg * 16] = av0;
        *(uint4*)&Asl[srow][sseg * 16 + 8] = av1;
        *(uint4*)&Wsl[srow][sseg * 16] = wv0;
        *(uint4*)&Wsl[srow][sseg * 16 + 8] = wv1;
        __syncthreads();
        uint4 nav0, nav1, nwv0, nwv1;
        bool more = (k0 + 64 < K);
        if (more) {
            nav0 = *(const uint4*)(Abase + k0 + 64);
            nav1 = *(const uint4*)(Abase + k0 + 72);
            nwv0 = *(const uint4*)(Wbase + k0 + 64);
            nwv1 = *(const uint4*)(Wbase + k0 + 72);
        }
#pragma unroll
        for (int kk = 0; kk < 2; kk++) {
            bf16x8 af[2], bf[2];
#pragma unroll
            for (int fi = 0; fi < 2; fi++) af[fi] = *(bf16x8*)&Asl[wm * 32 + fi * 16 + c][kk * 32 + g * 8];
#pragma unroll
            for (int fj = 0; fj < 2; fj++) bf[fj] = *(bf16x8*)&Wsl[wn * 32 + fj * 16 + c][kk * 32 + g * 8];
#pragma unroll
            for (int fi = 0; fi < 2; fi++)
#pragma unroll
                for (int fj = 0; fj < 2; fj++)
                    acc[fi][fj] = __builtin_amdgcn_mfma_f32_16x16x32_bf16(af[fi], bf[fj], acc[fi][fj], 0, 0, 0);
        }
        if (more) { av0 = nav0; av1 = nav1; wv0 = nwv0; wv1 = nwv1; }
    }

#pragma unroll
    for (int fi = 0; fi < 2; fi++) {
#pragma unroll
        for (int fj = 0; fj < 2; fj++) {
            int n = n0 + wn * 32 + fj * 16 + c;
#pragma unroll
            for (int i = 0; i < 4; i++) {
                int m = m0 + wm * 32 + fi * 16 + 4 * g + i;
                O[(size_t)m * N + n] = f2b(acc[fi][fj][i]);
            }
        }
    }
}

// ---------- fused q|y2 GEMM: W=[768][384], reg-prefetch ----------
__global__ __launch_bounds__(256) void gemm_qy2(const ushort_t* __restrict__ A,
                                                const ushort_t* __restrict__ W,
                                                const float* __restrict__ sr2_b,
                                                ushort_t* __restrict__ qb,
                                                float* __restrict__ y2f,
                                                int M, float qscale) {
    const int K = 384;
    __shared__ bf16_t Asl[64][72];
    __shared__ bf16_t Wsl[64][72];
    int tid = threadIdx.x;
    int wave = tid >> 6, lane = tid & 63, g = lane >> 4, c = lane & 15;
    int wm = wave >> 1, wn = wave & 1;
    int m0 = blockIdx.y * 64, n0 = blockIdx.x * 64;
    int srow = tid >> 2, sseg = tid & 3;
    const ushort_t* Abase = A + (size_t)(m0 + srow) * K + sseg * 16;
    const ushort_t* Wbase = W + (size_t)(n0 + srow) * K + sseg * 16;

    f32x4 acc[2][2];
#pragma unroll
    for (int i = 0; i < 2; i++)
#pragma unroll
        for (int j = 0; j < 2; j++) acc[i][j] = f32x4{0.f, 0.f, 0.f, 0.f};

    uint4 av0 = *(const uint4*)Abase, av1 = *(const uint4*)(Abase + 8);
    uint4 wv0 = *(const uint4*)Wbase, wv1 = *(const uint4*)(Wbase + 8);
    for (int k0 = 0; k0 < K; k0 += 64) {
        __syncthreads();
        *(uint4*)&Asl[srow][sseg * 16] = av0;
        *(uint4*)&Asl[srow][sseg * 16 + 8] = av1;
        *(uint4*)&Wsl[srow][sseg * 16] = wv0;
        *(uint4*)&Wsl[srow][sseg * 16 + 8] = wv1;
        __syncthreads();
        uint4 nav0, nav1, nwv0, nwv1;
        bool more = (k0 + 64 < K);
        if (more) {
            nav0 = *(const uint4*)(Abase + k0 + 64);
            nav1 = *(const uint4*)(Abase + k0 + 72);
            nwv0 = *(const uint4*)(Wbase + k0 + 64);
            nwv1 = *(const uint4*)(Wbase + k0 + 72);
        }
#pragma unroll
        for (int kk = 0; kk < 2; kk++) {
            bf16x8 af[2], bf[2];
#pragma unroll
            for (int fi = 0; fi < 2; fi++) af[fi] = *(bf16x8*)&Asl[wm * 32 + fi * 16 + c][kk * 32 + g * 8];
#pragma unroll
            for (int fj = 0; fj < 2; fj++) bf[fj] = *(bf16x8*)&Wsl[wn * 32 + fj * 16 + c][kk * 32 + g * 8];
#pragma unroll
            for (int fi = 0; fi < 2; fi++)
#pragma unroll
                for (int fj = 0; fj < 2; fj++)
                    acc[fi][fj] = __builtin_amdgcn_mfma_f32_16x16x32_bf16(af[fi], bf[fj], acc[fi][fj], 0, 0, 0);
        }
        if (more) { av0 = nav0; av1 = nav1; wv0 = nwv0; wv1 = nwv1; }
    }

    int isq = (n0 < 384);
#pragma unroll
    for (int fi = 0; fi < 2; fi++) {
#pragma unroll
        for (int fj = 0; fj < 2; fj++) {
            int n = n0 + wn * 32 + fj * 16 + c;
#pragma unroll
            for (int i = 0; i < 4; i++) {
                int m = m0 + wm * 32 + fi * 16 + 4 * g + i;
                float v = acc[fi][fj][i];
                if (isq) {
                    qb[(size_t)m * 384 + n] = f2b(v * qscale);
                } else {
                    y2f[(size_t)m * 384 + (n - 384)] = v + sr2_b[n - 384];
                }
            }
        }
    }
}

// ---------- FUSED depthwise 3x3x3 conv + transpose: kv -> vt directly ----------
// grid (72, 1, 2): bx<64 -> branch2 tile (S=4096), else branch1 (S=512). 256 threads.
// Computes vmod = v + dwconv(v) for a 64-row x 192-ch tile into LDS, writes vt[b][c][n].
__global__ __launch_bounds__(256) void dwconv_t_kernel(
    const ushort_t* __restrict__ v2in, const float* __restrict__ w2, const float* __restrict__ b2,
    ushort_t* __restrict__ vt2,
    const ushort_t* __restrict__ v1in, const float* __restrict__ w1, const float* __restrict__ b1,
    ushort_t* __restrict__ vt1)
{
    __shared__ ushort_t t_lds[192][66];
    int bx = blockIdx.x, b = blockIdx.z;
    const ushort_t* vin; const float* wt; const float* bias; ushort_t* vt;
    int S, n0, Hs, Wsz, Ds;
    if (bx < 64) { vin = v2in; wt = w2; bias = b2; vt = vt2; S = 4096; n0 = bx * 64; Hs = 16; Wsz = 16; Ds = 16; }
    else         { vin = v1in; wt = w1; bias = b1; vt = vt1; S = 512;  n0 = (bx - 64) * 64; Hs = 8; Wsz = 8; Ds = 8; }
    int tid = threadIdx.x;

    // compute: 64 rows x 192 channels = 12288 outputs, 48 per thread; c2 fastest (coalesced reads)
#pragma unroll
    for (int it = 0; it < 48; it++) {
        int idx = tid + it * 256;
        int c2 = idx % 192, nloc = idx / 192;
        int n = n0 + nloc;
        int dz = n % Ds, wy = (n / Ds) % Wsz, hx = n / (Wsz * Ds);
        float center = b2f(vin[(size_t)(b * S + n) * 384 + c2]);
        float acc = bias[c2];
        for (int kh = -1; kh <= 1; kh++) {
            int h2 = hx + kh; if (h2 < 0 || h2 >= Hs) continue;
            for (int kw = -1; kw <= 1; kw++) {
                int w2c = wy + kw; if (w2c < 0 || w2c >= Wsz) continue;
                for (int kd = -1; kd <= 1; kd++) {
                    int d2 = dz + kd; if (d2 < 0 || d2 >= Ds) continue;
                    int nn = (h2 * Wsz + w2c) * Ds + d2;
                    acc += b2f(vin[(size_t)(b * S + nn) * 384 + c2]) *
                           wt[c2 * 27 + (kh + 1) * 9 + (kw + 1) * 3 + (kd + 1)];
                }
            }
        }
        t_lds[c2][nloc] = f2b(center + acc);
    }
    __syncthreads();
    // write transposed: c-major rows of 64 contiguous n (128B per row)
#pragma unroll
    for (int it = 0; it < 48; it++) {
        int idx = tid + it * 256;
        int cc = idx >> 6, j = idx & 63;
        vt[((size_t)b * 192 + cc) * S + n0 + j] = t_lds[cc][j];
    }
}

// ---------- MFMA flash attention v5s (verified plateau config) ----------
__global__ __launch_bounds__(256, 4) void attn_mfma5s(
    const ushort_t* __restrict__ qbuf,
    const ushort_t* __restrict__ kv1,
    const ushort_t* __restrict__ kv2,
    const ushort_t* __restrict__ vt1,
    const ushort_t* __restrict__ vt2,
    ushort_t* __restrict__ obuf)
{
    __shared__ __align__(16) char lds_raw[18432];
    bf16_t (*P)[32][72] = (bf16_t (*)[32][72])lds_raw;
    float (*CF)[64][14] = (float (*)[64][14])lds_raw;

    const int N = 4096;
    int tid = threadIdx.x;
    int q0 = blockIdx.x * 32, hl = 7 - blockIdx.y, b = blockIdx.z;
    int wave = tid >> 6, lane = tid & 63, g = lane >> 4, c = lane & 15;
    int br2 = hl >> 2;
    int NK = br2 ? 4096 : 512;
    const ushort_t* kbuf = br2 ? kv2 : kv1;
    const ushort_t* vtb  = br2 ? vt2 : vt1;
    int hloc = hl & 3;
    int NKc = NK >> 2;
    int kb0 = wave * NKc;
    int nkt = NKc >> 6;

    union { uint4 u; bf16x8 v; } zz; zz.u = uint4{0u, 0u, 0u, 0u};
    const bf16x8 zero8 = zz.v;

    bf16x8 bq0[2], bq1[2];
#pragma unroll
    for (int qg = 0; qg < 2; qg++) {
        const ushort_t* qrowp = qbuf + ((size_t)b * N + q0 + qg * 16 + c) * 384 + hl * 48;
        bq0[qg] = *(const bf16x8*)(qrowp + g * 8);
        bq1[qg] = (g < 2) ? *(const bf16x8*)(qrowp + 32 + g * 8) : zero8;
    }

    f32x4 of[3][2];
#pragma unroll
    for (int dt = 0; dt < 3; dt++)
#pragma unroll
        for (int qg = 0; qg < 2; qg++) of[dt][qg] = f32x4{0.f, 0.f, 0.f, 0.f};
    float l_acc[2] = {0.f, 0.f};

    const ushort_t* kp = kbuf + ((size_t)b * NK + kb0 + c) * 384 + hloc * 48;
    const ushort_t* vp = vtb + ((size_t)b * 192 + hloc * 48 + c) * NK + kb0;

    for (int kt = 0; kt < nkt; kt++) {
        f32x4 sf[4][2];
#pragma unroll
        for (int t = 0; t < 4; t++)
#pragma unroll
            for (int qg = 0; qg < 2; qg++) sf[t][qg] = f32x4{0.f, 0.f, 0.f, 0.f};
        __builtin_amdgcn_s_setprio(1);
#pragma unroll
        for (int t = 0; t < 4; t++) {
            const ushort_t* kr = kp + (size_t)(kt * 64 + 16 * t) * 384;
            bf16x8 ak0 = *(const bf16x8*)(kr + g * 8);
            bf16x8 ak1 = (g < 2) ? *(const bf16x8*)(kr + 32 + g * 8) : zero8;
#pragma unroll
            for (int qg = 0; qg < 2; qg++) {
                sf[t][qg] = __builtin_amdgcn_mfma_f32_16x16x32_bf16(ak0, bq0[qg], sf[t][qg], 0, 0, 0);
                sf[t][qg] = __builtin_amdgcn_mfma_f32_16x16x32_bf16(ak1, bq1[qg], sf[t][qg], 0, 0, 0);
            }
        }
        __builtin_amdgcn_s_setprio(0);

#pragma unroll
        for (int qg = 0; qg < 2; qg++) {
#pragma unroll
            for (int t = 0; t < 4; t++) {
                union { ushort4 v; bf16_t h[4]; } pk;
#pragma unroll
                for (int i = 0; i < 4; i++) {
                    float p = exp2f(sf[t][qg][i]);
                    l_acc[qg] += p;
                    pk.h[i] = (bf16_t)p;
                }
                *(ushort4*)&P[wave][qg * 16 + c][16 * t + 4 * g] = pk.v;
            }
        }

        asm volatile("s_waitcnt lgkmcnt(0)" ::: "memory");

        bf16x8 pb0[2], pb1[2];
#pragma unroll
        for (int qg = 0; qg < 2; qg++) {
            pb0[qg] = *(bf16x8*)&P[wave][qg * 16 + c][g * 8];
            pb1[qg] = *(bf16x8*)&P[wave][qg * 16 + c][32 + g * 8];
        }
        __builtin_amdgcn_s_setprio(1);
#pragma unroll
        for (int dt = 0; dt < 3; dt++) {
            const ushort_t* vr = vp + (size_t)(16 * dt) * NK + kt * 64;
            bf16x8 av0 = *(const bf16x8*)(vr + g * 8);
            bf16x8 av1 = *(const bf16x8*)(vr + 32 + g * 8);
#pragma unroll
            for (int qg = 0; qg < 2; qg++) {
                of[dt][qg] = __builtin_amdgcn_mfma_f32_16x16x32_bf16(av0, pb0[qg], of[dt][qg], 0, 0, 0);
                of[dt][qg] = __builtin_amdgcn_mfma_f32_16x16x32_bf16(av1, pb1[qg], of[dt][qg], 0, 0, 0);
            }
        }
        __builtin_amdgcn_s_setprio(0);
    }

#pragma unroll
    for (int qg = 0; qg < 2; qg++) {
        l_acc[qg] += __shfl_xor(l_acc[qg], 16);
        l_acc[qg] += __shfl_xor(l_acc[qg], 32);
    }

#pragma unroll
    for (int qg = 0; qg < 2; qg++) {
        __syncthreads();
        float* cfp = &CF[wave][lane][0];
#pragma unroll
        for (int dt = 0; dt < 3; dt++)
#pragma unroll
            for (int i = 0; i < 4; i++) cfp[dt * 4 + i] = of[dt][qg][i];
        cfp[12] = l_acc[qg];
        __syncthreads();
        if (wave == 0) {
            float lsum = 0.f;
            float oc[12];
#pragma unroll
            for (int j = 0; j < 12; j++) oc[j] = 0.f;
#pragma unroll
            for (int w = 0; w < 4; w++) {
                lsum += CF[w][lane][12];
#pragma unroll
                for (int j = 0; j < 12; j++) oc[j] += CF[w][lane][j];
            }
            float rl = 1.f / lsum;
            int qrow = q0 + qg * 16 + c;
#pragma unroll
            for (int dt = 0; dt < 3; dt++) {
                union { ushort4 v; bf16_t h[4]; } pk;
#pragma unroll
                for (int i = 0; i < 4; i++) pk.h[i] = (bf16_t)(oc[dt * 4 + i] * rl);
                *(ushort4*)&obuf[((size_t)b * N + qrow) * 384 + hl * 48 + 16 * dt + 4 * g] = pk.v;
            }
        }
    }
}

// ---------- host ----------
extern "C" void kernel_launch(void* const* d_in, const int* in_sizes, int n_in,
                              void* d_out, int out_size, void* d_ws, size_t ws_size,
                              hipStream_t stream) {
    const int B = 2, N = 4096, C = 384, N1 = 512, HID = 1536;
    const float* x      = (const float*)d_in[0];
    const float* ln1_w  = (const float*)d_in[1];
    const float* ln1_b  = (const float*)d_in[2];
    const float* q_w    = (const float*)d_in[3];
    const float* sr1_w  = (const float*)d_in[4];
    const float* sr1_b  = (const float*)d_in[5];
    const float* n1_w   = (const float*)d_in[6];
    const float* n1_b   = (const float*)d_in[7];
    const float* sr2_w  = (const float*)d_in[8];
    const float* sr2_b  = (const float*)d_in[9];
    const float* n2_w   = (const float*)d_in[10];
    const float* n2_b   = (const float*)d_in[11];
    const float* kv1_w  = (const float*)d_in[12];
    const float* kv2_w  = (const float*)d_in[13];
    const float* lc1_w  = (const float*)d_in[14];
    const float* lc1_b  = (const float*)d_in[15];
    const float* lc2_w  = (const float*)d_in[16];
    const float* lc2_b  = (const float*)d_in[17];
    const float* proj_w = (const float*)d_in[18];
    const float* proj_b = (const float*)d_in[19];
    const float* ln2_w  = (const float*)d_in[20];
    const float* ln2_b  = (const float*)d_in[21];
    const float* fc1_w  = (const float*)d_in[22];
    const float* fc1_b  = (const float*)d_in[23];
    const float* fc2_w  = (const float*)d_in[24];
    const float* fc2_b  = (const float*)d_in[25];
    float* out = (float*)d_out;

    char* ws = (char*)d_ws;
    ushort_t* wbase = (ushort_t*)ws;
    ushort_t* wqy2 = wbase;
    ushort_t* wkv1 = wbase + 294912;
    ushort_t* wkv2 = wbase + 442368;
    ushort_t* wproj= wbase + 589824;
    ushort_t* wfc1 = wbase + 737280;
    ushort_t* wfc2 = wbase + 1327104;
    ushort_t* wsr1 = wbase + 1916928;
    ushort_t* xa_bf = (ushort_t*)(ws + 6193152);
    ushort_t* qbB   = (ushort_t*)(ws + 12484608);
    ushort_t* x2_bf = (ushort_t*)(ws + 18776064);
    ushort_t* kv2   = (ushort_t*)(ws + 25067520);
    ushort_t* kv1   = (ushort_t*)(ws + 34504704);
    ushort_t* x1_bf = (ushort_t*)(ws + 35684352);
    float*    y2f   = (float*)(ws + 36470784);
    ushort_t* A1    = (ushort_t*)(ws + 50626560);
    ushort_t* hid   = (ushort_t*)(ws + 56918016);
    ushort_t* vt2   = (ushort_t*)(ws + 82083840);
    ushort_t* vt1   = (ushort_t*)(ws + 85229568);
    float*    y1p   = (float*)(ws + 85622784);
    ushort_t* Obuf  = xa_bf;
    float*    xres  = y2f;
    ushort_t* xm_bf = A1;

    const float QSCALE = 0.14433756729740643f * 1.4426950408889634f;

    // 0. weights
    prep_weights<<<(3096576 + 255) / 256, 256, 0, stream>>>(q_w, sr2_w, kv1_w, kv2_w,
                                                            proj_w, fc1_w, fc2_w, sr1_w, wbase);
    // 1. xa = LN(x) -> bf16
    ln_kernel<<<B * N, 128, 0, stream>>>(x, ln1_w, ln1_b, nullptr, xa_bf, 0);
    // 2+3. fused q|y2
    gemm_qy2<<<dim3(12, 128), 256, 0, stream>>>(xa_bf, wqy2, sr2_b, qbB, y2f, B * N, QSCALE);
    // 4. x2 = gelu(LN(y2)) -> bf16
    ln_kernel<<<B * N, 128, 0, stream>>>(y2f, n2_w, n2_b, nullptr, x2_bf, 1);
    // 5. im2col + split-K sr1 GEMM
    im2col_kernel<<<(1024 * 3072 + 255) / 256, 256, 0, stream>>>(xa_bf, A1);
    gemm64sk<<<dim3(6, 16, 4), 256, 0, stream>>>(A1, wsr1, y1p);
    // 6. x1 = gelu(LN(sum partials + sr1_b)) -> bf16
    ln4_kernel<<<B * N1, 128, 0, stream>>>(y1p, sr1_b, n1_w, n1_b, x1_bf);
    // 7+8. merged kv projections (bf16)
    gemm_kv<<<dim3(6, 144), 256, 0, stream>>>(x2_bf, wkv2, kv2, x1_bf, wkv1, kv1);
    // 9/10. FUSED dwconv + transpose -> vt (one launch)
    dwconv_t_kernel<<<dim3(72, 1, 2), 256, 0, stream>>>(kv2 + 192, lc2_w, lc2_b, vt2,
                                                        kv1 + 192, lc1_w, lc1_b, vt1);
    // 11. attention v5s
    attn_mfma5s<<<dim3(N / 32, 8, B), 256, 0, stream>>>(qbB, kv1, kv2, vt1, vt2, Obuf);
    // 13. xres = x + O @ proj_w^T + proj_b (f32)
    gemm64<<<dim3(6, 128), 256, 0, stream>>>(Obuf, wproj, proj_b, x,
                                             xres, nullptr, B * N, C, C, 0, 1.f);
    // 14. xm = LN(xres) -> bf16
    ln_kernel<<<B * N, 128, 0, stream>>>(xres, ln2_w, ln2_b, nullptr, xm_bf, 0);
    // 15. hid = gelu(xm @ fc1^T + b) (bf16)
    mfma_gemm<<<dim3(12, 64), 256, 0, stream>>>(xm_bf, wfc1, fc1_b, nullptr,
                                                nullptr, hid, B * N, HID, C, 1);
    // 16. out = xres + hid @ fc2^T + b (f32 -> d_out)
    gemm64<<<dim3(6, 128), 256, 0, stream>>>(hid, wfc2, fc2_b, xres,
                                             out, nullptr, B * N, C, HID, 0, 1.f);
}

// Round 20
// 313.583 us; speedup vs baseline: 1.5851x; 1.5851x over previous
//
#include <hip/hip_runtime.h>

typedef unsigned short ushort_t;
typedef unsigned int uint_t;
typedef __bf16 bf16_t;
typedef __bf16 bf16x8 __attribute__((ext_vector_type(8)));
typedef float f32x4 __attribute__((ext_vector_type(4)));

// ---------- helpers ----------
__device__ __forceinline__ float b2f(ushort_t u) {
    union { uint_t i; float f; } v; v.i = ((uint_t)u) << 16; return v.f;
}
__device__ __forceinline__ ushort_t f2b(float f) {
    union { float f; uint_t i; } v; v.f = f;
    uint_t r = v.i + 0x7fffu + ((v.i >> 16) & 1u);
    return (ushort_t)(r >> 16);
}
__device__ __forceinline__ float gelu_exact(float x) {
    return 0.5f * x * (1.0f + erff(x * 0.70710678118654752f));
}

// ---------- all weight conversions in ONE launch ----------
__global__ void prep_weights(const float* __restrict__ q_w, const float* __restrict__ sr2_w,
                             const float* __restrict__ kv1_w, const float* __restrict__ kv2_w,
                             const float* __restrict__ proj_w, const float* __restrict__ fc1_w,
                             const float* __restrict__ fc2_w, const float* __restrict__ sr1_w,
                             ushort_t* __restrict__ dst) {
    int gid = blockIdx.x * 256 + threadIdx.x;
    int i = gid;
    if (i < 147456) { dst[gid] = f2b(q_w[i]); return; }
    i -= 147456;
    if (i < 147456) { dst[gid] = f2b(sr2_w[i]); return; }
    i -= 147456;
    if (i < 147456) { dst[gid] = f2b(kv1_w[i]); return; }
    i -= 147456;
    if (i < 147456) { dst[gid] = f2b(kv2_w[i]); return; }
    i -= 147456;
    if (i < 147456) { dst[gid] = f2b(proj_w[i]); return; }
    i -= 147456;
    if (i < 589824) { dst[gid] = f2b(fc1_w[i]); return; }
    i -= 589824;
    if (i < 589824) { dst[gid] = f2b(fc2_w[i]); return; }
    i -= 589824;
    if (i < 1179648) {
        int co = i / 3072, r = i % 3072, kk = r / 384, ci = r % 384;
        dst[gid] = f2b(sr1_w[((size_t)co * 384 + ci) * 8 + kk]);
    }
}

// ---------- im2col for sr1 ----------
__global__ void im2col_kernel(const ushort_t* __restrict__ xa, ushort_t* __restrict__ A1) {
    int gid = blockIdx.x * 256 + threadIdx.x;
    if (gid >= 1024 * 3072) return;
    int m = gid / 3072, r = gid % 3072, kk = r / 384, ci = r % 384;
    int b = m >> 9, n1 = m & 511;
    int ho = n1 >> 6, wo = (n1 >> 3) & 7, dz = n1 & 7;
    int n = ((2 * ho + ((kk >> 2) & 1)) << 8) + ((2 * wo + ((kk >> 1) & 1)) << 4) + (2 * dz + (kk & 1));
    A1[gid] = xa[((size_t)b * 4096 + n) * 384 + ci];
}

// ---------- LayerNorm (+ optional GELU); C = 384 ----------
__global__ __launch_bounds__(128) void ln_kernel(const float* __restrict__ in,
                                                 const float* __restrict__ w,
                                                 const float* __restrict__ b,
                                                 float* __restrict__ outf,
                                                 ushort_t* __restrict__ outb, int act) {
    const int C = 384;
    int row = blockIdx.x, tid = threadIdx.x;
    size_t base = (size_t)row * C;
    float x[3], s = 0.f, s2 = 0.f;
#pragma unroll
    for (int i = 0; i < 3; i++) {
        int c = tid + i * 128;
        float v = in[base + c];
        x[i] = v; s += v; s2 += v * v;
    }
    for (int off = 32; off; off >>= 1) { s += __shfl_down(s, off); s2 += __shfl_down(s2, off); }
    __shared__ float sc[4];
    int lane = tid & 63, wid = tid >> 6;
    if (lane == 0) { sc[wid] = s; sc[wid + 2] = s2; }
    __syncthreads();
    float ts = sc[0] + sc[1], ts2 = sc[2] + sc[3];
    float mean = ts / C;
    float var = ts2 / C - mean * mean;
    float rstd = rsqrtf(var + 1e-5f);
#pragma unroll
    for (int i = 0; i < 3; i++) {
        int c = tid + i * 128;
        float v = (x[i] - mean) * rstd * w[c] + b[c];
        if (act) v = gelu_exact(v);
        if (outf) outf[base + c] = v;
        if (outb) outb[base + c] = f2b(v);
    }
}

// ---------- LN over sum of 4 split-K partials + conv bias, then GELU -> bf16 ----------
__global__ __launch_bounds__(128) void ln4_kernel(const float* __restrict__ p,
                                                  const float* __restrict__ cbias,
                                                  const float* __restrict__ w,
                                                  const float* __restrict__ b,
                                                  ushort_t* __restrict__ outb) {
    const int C = 384;
    const size_t CH = (size_t)1024 * 384;
    int row = blockIdx.x, tid = threadIdx.x;
    size_t base = (size_t)row * C;
    float x[3], s = 0.f, s2 = 0.f;
#pragma unroll
    for (int i = 0; i < 3; i++) {
        int c = tid + i * 128;
        float v = ((p[base + c] + p[CH + base + c]) + (p[2 * CH + base + c] + p[3 * CH + base + c]))
                  + cbias[c];
        x[i] = v; s += v; s2 += v * v;
    }
    for (int off = 32; off; off >>= 1) { s += __shfl_down(s, off); s2 += __shfl_down(s2, off); }
    __shared__ float sc[4];
    int lane = tid & 63, wid = tid >> 6;
    if (lane == 0) { sc[wid] = s; sc[wid + 2] = s2; }
    __syncthreads();
    float ts = sc[0] + sc[1], ts2 = sc[2] + sc[3];
    float mean = ts / C;
    float var = ts2 / C - mean * mean;
    float rstd = rsqrtf(var + 1e-5f);
#pragma unroll
    for (int i = 0; i < 3; i++) {
        int c = tid + i * 128;
        float v = (x[i] - mean) * rstd * w[c] + b[c];
        outb[base + c] = f2b(gelu_exact(v));
    }
}

// ---------- MFMA GEMM 128x128, BK=32, reg-prefetch (used for fc1) ----------
__global__ __launch_bounds__(256) void mfma_gemm(const ushort_t* __restrict__ A,
                                                 const ushort_t* __restrict__ W,
                                                 const float* __restrict__ bias,
                                                 const float* __restrict__ res,
                                                 float* __restrict__ outf,
                                                 ushort_t* __restrict__ outb,
                                                 int M, int N, int K, int act) {
    __shared__ bf16_t Asl[128][40];
    __shared__ bf16_t Wsl[128][40];
    int tid = threadIdx.x;
    int wave = tid >> 6, lane = tid & 63, g = lane >> 4, c = lane & 15;
    int wm = wave >> 1, wn = wave & 1;
    int m0 = blockIdx.y * 128, n0 = blockIdx.x * 128;
    int srow = tid >> 1, sseg = tid & 1;
    const ushort_t* Abase = A + (size_t)(m0 + srow) * K + sseg * 16;
    const ushort_t* Wbase = W + (size_t)(n0 + srow) * K + sseg * 16;

    f32x4 acc[4][4];
#pragma unroll
    for (int i = 0; i < 4; i++)
#pragma unroll
        for (int j = 0; j < 4; j++) acc[i][j] = f32x4{0.f, 0.f, 0.f, 0.f};

    uint4 av0 = *(const uint4*)Abase, av1 = *(const uint4*)(Abase + 8);
    uint4 wv0 = *(const uint4*)Wbase, wv1 = *(const uint4*)(Wbase + 8);
    for (int k0 = 0; k0 < K; k0 += 32) {
        __syncthreads();
        *(uint4*)&Asl[srow][sseg * 16] = av0;
        *(uint4*)&Asl[srow][sseg * 16 + 8] = av1;
        *(uint4*)&Wsl[srow][sseg * 16] = wv0;
        *(uint4*)&Wsl[srow][sseg * 16 + 8] = wv1;
        __syncthreads();
        uint4 nav0, nav1, nwv0, nwv1;
        bool more = (k0 + 32 < K);
        if (more) {
            nav0 = *(const uint4*)(Abase + k0 + 32);
            nav1 = *(const uint4*)(Abase + k0 + 40);
            nwv0 = *(const uint4*)(Wbase + k0 + 32);
            nwv1 = *(const uint4*)(Wbase + k0 + 40);
        }
        bf16x8 af[4], bf[4];
#pragma unroll
        for (int fi = 0; fi < 4; fi++) af[fi] = *(bf16x8*)&Asl[wm * 64 + fi * 16 + c][g * 8];
#pragma unroll
        for (int fj = 0; fj < 4; fj++) bf[fj] = *(bf16x8*)&Wsl[wn * 64 + fj * 16 + c][g * 8];
#pragma unroll
        for (int fi = 0; fi < 4; fi++)
#pragma unroll
            for (int fj = 0; fj < 4; fj++)
                acc[fi][fj] = __builtin_amdgcn_mfma_f32_16x16x32_bf16(af[fi], bf[fj], acc[fi][fj], 0, 0, 0);
        if (more) { av0 = nav0; av1 = nav1; wv0 = nwv0; wv1 = nwv1; }
    }

#pragma unroll
    for (int fi = 0; fi < 4; fi++) {
#pragma unroll
        for (int fj = 0; fj < 4; fj++) {
            int n = n0 + wn * 64 + fj * 16 + c;
            float bv = bias ? bias[n] : 0.f;
#pragma unroll
            for (int i = 0; i < 4; i++) {
                int m = m0 + wm * 64 + fi * 16 + 4 * g + i;
                float v = acc[fi][fj][i] + bv;
                if (act == 1) v = gelu_exact(v);
                size_t idx = (size_t)m * N + n;
                if (res) v += res[idx];
                if (outf) outf[idx] = v;
                if (outb) outb[idx] = f2b(v);
            }
        }
    }
}

// ---------- MFMA GEMM 64x64, BK=64, reg-prefetch (+output scale) ----------
__global__ __launch_bounds__(256) void gemm64(const ushort_t* __restrict__ A,
                                              const ushort_t* __restrict__ W,
                                              const float* __restrict__ bias,
                                              const float* __restrict__ res,
                                              float* __restrict__ outf,
                                              ushort_t* __restrict__ outb,
                                              int M, int N, int K, int act, float oscale) {
    __shared__ bf16_t Asl[64][72];
    __shared__ bf16_t Wsl[64][72];
    int tid = threadIdx.x;
    int wave = tid >> 6, lane = tid & 63, g = lane >> 4, c = lane & 15;
    int wm = wave >> 1, wn = wave & 1;
    int m0 = blockIdx.y * 64, n0 = blockIdx.x * 64;
    int srow = tid >> 2, sseg = tid & 3;
    const ushort_t* Abase = A + (size_t)(m0 + srow) * K + sseg * 16;
    const ushort_t* Wbase = W + (size_t)(n0 + srow) * K + sseg * 16;

    f32x4 acc[2][2];
#pragma unroll
    for (int i = 0; i < 2; i++)
#pragma unroll
        for (int j = 0; j < 2; j++) acc[i][j] = f32x4{0.f, 0.f, 0.f, 0.f};

    uint4 av0 = *(const uint4*)Abase, av1 = *(const uint4*)(Abase + 8);
    uint4 wv0 = *(const uint4*)Wbase, wv1 = *(const uint4*)(Wbase + 8);
    for (int k0 = 0; k0 < K; k0 += 64) {
        __syncthreads();
        *(uint4*)&Asl[srow][sseg * 16] = av0;
        *(uint4*)&Asl[srow][sseg * 16 + 8] = av1;
        *(uint4*)&Wsl[srow][sseg * 16] = wv0;
        *(uint4*)&Wsl[srow][sseg * 16 + 8] = wv1;
        __syncthreads();
        uint4 nav0, nav1, nwv0, nwv1;
        bool more = (k0 + 64 < K);
        if (more) {
            nav0 = *(const uint4*)(Abase + k0 + 64);
            nav1 = *(const uint4*)(Abase + k0 + 72);
            nwv0 = *(const uint4*)(Wbase + k0 + 64);
            nwv1 = *(const uint4*)(Wbase + k0 + 72);
        }
#pragma unroll
        for (int kk = 0; kk < 2; kk++) {
            bf16x8 af[2], bf[2];
#pragma unroll
            for (int fi = 0; fi < 2; fi++) af[fi] = *(bf16x8*)&Asl[wm * 32 + fi * 16 + c][kk * 32 + g * 8];
#pragma unroll
            for (int fj = 0; fj < 2; fj++) bf[fj] = *(bf16x8*)&Wsl[wn * 32 + fj * 16 + c][kk * 32 + g * 8];
#pragma unroll
            for (int fi = 0; fi < 2; fi++)
#pragma unroll
                for (int fj = 0; fj < 2; fj++)
                    acc[fi][fj] = __builtin_amdgcn_mfma_f32_16x16x32_bf16(af[fi], bf[fj], acc[fi][fj], 0, 0, 0);
        }
        if (more) { av0 = nav0; av1 = nav1; wv0 = nwv0; wv1 = nwv1; }
    }

#pragma unroll
    for (int fi = 0; fi < 2; fi++) {
#pragma unroll
        for (int fj = 0; fj < 2; fj++) {
            int n = n0 + wn * 32 + fj * 16 + c;
            float bv = bias ? bias[n] : 0.f;
#pragma unroll
            for (int i = 0; i < 4; i++) {
                int m = m0 + wm * 32 + fi * 16 + 4 * g + i;
                float v = (acc[fi][fj][i] + bv) * oscale;
                if (act == 1) v = gelu_exact(v);
                size_t idx = (size_t)m * N + n;
                if (res) v += res[idx];
                if (outf) outf[idx] = v;
                if (outb) outb[idx] = f2b(v);
            }
        }
    }
}

// ---------- split-K GEMM for sr1: K=3072 in 4 chunks of 768; f32 partials ----------
__global__ __launch_bounds__(256) void gemm64sk(const ushort_t* __restrict__ A,
                                                const ushort_t* __restrict__ W,
                                                float* __restrict__ yp) {
    const int K = 3072, N = 384, KC = 768;
    __shared__ bf16_t Asl[64][72];
    __shared__ bf16_t Wsl[64][72];
    int tid = threadIdx.x;
    int wave = tid >> 6, lane = tid & 63, g = lane >> 4, c = lane & 15;
    int wm = wave >> 1, wn = wave & 1;
    int m0 = blockIdx.y * 64, n0 = blockIdx.x * 64, kc = blockIdx.z;
    int kbeg = kc * KC;
    int srow = tid >> 2, sseg = tid & 3;
    const ushort_t* Abase = A + (size_t)(m0 + srow) * K + kbeg + sseg * 16;
    const ushort_t* Wbase = W + (size_t)(n0 + srow) * K + kbeg + sseg * 16;
    float* out = yp + (size_t)kc * 1024 * 384;

    f32x4 acc[2][2];
#pragma unroll
    for (int i = 0; i < 2; i++)
#pragma unroll
        for (int j = 0; j < 2; j++) acc[i][j] = f32x4{0.f, 0.f, 0.f, 0.f};

    uint4 av0 = *(const uint4*)Abase, av1 = *(const uint4*)(Abase + 8);
    uint4 wv0 = *(const uint4*)Wbase, wv1 = *(const uint4*)(Wbase + 8);
    for (int k0 = 0; k0 < KC; k0 += 64) {
        __syncthreads();
        *(uint4*)&Asl[srow][sseg * 16] = av0;
        *(uint4*)&Asl[srow][sseg * 16 + 8] = av1;
        *(uint4*)&Wsl[srow][sseg * 16] = wv0;
        *(uint4*)&Wsl[srow][sseg * 16 + 8] = wv1;
        __syncthreads();
        uint4 nav0, nav1, nwv0, nwv1;
        bool more = (k0 + 64 < KC);
        if (more) {
            nav0 = *(const uint4*)(Abase + k0 + 64);
            nav1 = *(const uint4*)(Abase + k0 + 72);
            nwv0 = *(const uint4*)(Wbase + k0 + 64);
            nwv1 = *(const uint4*)(Wbase + k0 + 72);
        }
#pragma unroll
        for (int kk = 0; kk < 2; kk++) {
            bf16x8 af[2], bf[2];
#pragma unroll
            for (int fi = 0; fi < 2; fi++) af[fi] = *(bf16x8*)&Asl[wm * 32 + fi * 16 + c][kk * 32 + g * 8];
#pragma unroll
            for (int fj = 0; fj < 2; fj++) bf[fj] = *(bf16x8*)&Wsl[wn * 32 + fj * 16 + c][kk * 32 + g * 8];
#pragma unroll
            for (int fi = 0; fi < 2; fi++)
#pragma unroll
                for (int fj = 0; fj < 2; fj++)
                    acc[fi][fj] = __builtin_amdgcn_mfma_f32_16x16x32_bf16(af[fi], bf[fj], acc[fi][fj], 0, 0, 0);
        }
        if (more) { av0 = nav0; av1 = nav1; wv0 = nwv0; wv1 = nwv1; }
    }

#pragma unroll
    for (int fi = 0; fi < 2; fi++) {
#pragma unroll
        for (int fj = 0; fj < 2; fj++) {
            int n = n0 + wn * 32 + fj * 16 + c;
#pragma unroll
            for (int i = 0; i < 4; i++) {
                int m = m0 + wm * 32 + fi * 16 + 4 * g + i;
                out[(size_t)m * N + n] = acc[fi][fj][i];
            }
        }
    }
}

// ---------- merged kv projections: y<128 -> kv2 (M=8192), else kv1 (M=1024) ----------
__global__ __launch_bounds__(256) void gemm_kv(const ushort_t* __restrict__ A2,
                                               const ushort_t* __restrict__ W2,
                                               ushort_t* __restrict__ O2,
                                               const ushort_t* __restrict__ A1,
                                               const ushort_t* __restrict__ W1,
                                               ushort_t* __restrict__ O1) {
    const int K = 384, N = 384;
    __shared__ bf16_t Asl[64][72];
    __shared__ bf16_t Wsl[64][72];
    int tid = threadIdx.x;
    int wave = tid >> 6, lane = tid & 63, g = lane >> 4, c = lane & 15;
    int wm = wave >> 1, wn = wave & 1;
    int by = blockIdx.y;
    const ushort_t* A; const ushort_t* W; ushort_t* O; int m0;
    if (by < 128) { A = A2; W = W2; O = O2; m0 = by * 64; }
    else          { A = A1; W = W1; O = O1; m0 = (by - 128) * 64; }
    int n0 = blockIdx.x * 64;
    int srow = tid >> 2, sseg = tid & 3;
    const ushort_t* Abase = A + (size_t)(m0 + srow) * K + sseg * 16;
    const ushort_t* Wbase = W + (size_t)(n0 + srow) * K + sseg * 16;

    f32x4 acc[2][2];
#pragma unroll
    for (int i = 0; i < 2; i++)
#pragma unroll
        for (int j = 0; j < 2; j++) acc[i][j] = f32x4{0.f, 0.f, 0.f, 0.f};

    uint4 av0 = *(const uint4*)Abase, av1 = *(const uint4*)(Abase + 8);
    uint4 wv0 = *(const uint4*)Wbase, wv1 = *(const uint4*)(Wbase + 8);
    for (int k0 = 0; k0 < K; k0 += 64) {
        __syncthreads();
        *(uint4*)&Asl[srow][sseg * 16] = av0;
        *(uint4*)&Asl[srow][sseg * 16 + 8] = av1;
        *(uint4*)&Wsl[srow][sseg * 16] = wv0;
        *(uint4*)&Wsl[srow][sseg * 16 + 8] = wv1;
        __syncthreads();
        uint4 nav0, nav1, nwv0, nwv1;
        bool more = (k0 + 64 < K);
        if (more) {
            nav0 = *(const uint4*)(Abase + k0 + 64);
            nav1 = *(const uint4*)(Abase + k0 + 72);
            nwv0 = *(const uint4*)(Wbase + k0 + 64);
            nwv1 = *(const uint4*)(Wbase + k0 + 72);
        }
#pragma unroll
        for (int kk = 0; kk < 2; kk++) {
            bf16x8 af[2], bf[2];
#pragma unroll
            for (int fi = 0; fi < 2; fi++) af[fi] = *(bf16x8*)&Asl[wm * 32 + fi * 16 + c][kk * 32 + g * 8];
#pragma unroll
            for (int fj = 0; fj < 2; fj++) bf[fj] = *(bf16x8*)&Wsl[wn * 32 + fj * 16 + c][kk * 32 + g * 8];
#pragma unroll
            for (int fi = 0; fi < 2; fi++)
#pragma unroll
                for (int fj = 0; fj < 2; fj++)
                    acc[fi][fj] = __builtin_amdgcn_mfma_f32_16x16x32_bf16(af[fi], bf[fj], acc[fi][fj], 0, 0, 0);
        }
        if (more) { av0 = nav0; av1 = nav1; wv0 = nwv0; wv1 = nwv1; }
    }

#pragma unroll
    for (int fi = 0; fi < 2; fi++) {
#pragma unroll
        for (int fj = 0; fj < 2; fj++) {
            int n = n0 + wn * 32 + fj * 16 + c;
#pragma unroll
            for (int i = 0; i < 4; i++) {
                int m = m0 + wm * 32 + fi * 16 + 4 * g + i;
                O[(size_t)m * N + n] = f2b(acc[fi][fj][i]);
            }
        }
    }
}

// ---------- fused q|y2 GEMM: W=[768][384], reg-prefetch ----------
__global__ __launch_bounds__(256) void gemm_qy2(const ushort_t* __restrict__ A,
                                                const ushort_t* __restrict__ W,
                                                const float* __restrict__ sr2_b,
                                                ushort_t* __restrict__ qb,
                                                float* __restrict__ y2f,
                                                int M, float qscale) {
    const int K = 384;
    __shared__ bf16_t Asl[64][72];
    __shared__ bf16_t Wsl[64][72];
    int tid = threadIdx.x;
    int wave = tid >> 6, lane = tid & 63, g = lane >> 4, c = lane & 15;
    int wm = wave >> 1, wn = wave & 1;
    int m0 = blockIdx.y * 64, n0 = blockIdx.x * 64;
    int srow = tid >> 2, sseg = tid & 3;
    const ushort_t* Abase = A + (size_t)(m0 + srow) * K + sseg * 16;
    const ushort_t* Wbase = W + (size_t)(n0 + srow) * K + sseg * 16;

    f32x4 acc[2][2];
#pragma unroll
    for (int i = 0; i < 2; i++)
#pragma unroll
        for (int j = 0; j < 2; j++) acc[i][j] = f32x4{0.f, 0.f, 0.f, 0.f};

    uint4 av0 = *(const uint4*)Abase, av1 = *(const uint4*)(Abase + 8);
    uint4 wv0 = *(const uint4*)Wbase, wv1 = *(const uint4*)(Wbase + 8);
    for (int k0 = 0; k0 < K; k0 += 64) {
        __syncthreads();
        *(uint4*)&Asl[srow][sseg * 16] = av0;
        *(uint4*)&Asl[srow][sseg * 16 + 8] = av1;
        *(uint4*)&Wsl[srow][sseg * 16] = wv0;
        *(uint4*)&Wsl[srow][sseg * 16 + 8] = wv1;
        __syncthreads();
        uint4 nav0, nav1, nwv0, nwv1;
        bool more = (k0 + 64 < K);
        if (more) {
            nav0 = *(const uint4*)(Abase + k0 + 64);
            nav1 = *(const uint4*)(Abase + k0 + 72);
            nwv0 = *(const uint4*)(Wbase + k0 + 64);
            nwv1 = *(const uint4*)(Wbase + k0 + 72);
        }
#pragma unroll
        for (int kk = 0; kk < 2; kk++) {
            bf16x8 af[2], bf[2];
#pragma unroll
            for (int fi = 0; fi < 2; fi++) af[fi] = *(bf16x8*)&Asl[wm * 32 + fi * 16 + c][kk * 32 + g * 8];
#pragma unroll
            for (int fj = 0; fj < 2; fj++) bf[fj] = *(bf16x8*)&Wsl[wn * 32 + fj * 16 + c][kk * 32 + g * 8];
#pragma unroll
            for (int fi = 0; fi < 2; fi++)
#pragma unroll
                for (int fj = 0; fj < 2; fj++)
                    acc[fi][fj] = __builtin_amdgcn_mfma_f32_16x16x32_bf16(af[fi], bf[fj], acc[fi][fj], 0, 0, 0);
        }
        if (more) { av0 = nav0; av1 = nav1; wv0 = nwv0; wv1 = nwv1; }
    }

    int isq = (n0 < 384);
#pragma unroll
    for (int fi = 0; fi < 2; fi++) {
#pragma unroll
        for (int fj = 0; fj < 2; fj++) {
            int n = n0 + wn * 32 + fj * 16 + c;
#pragma unroll
            for (int i = 0; i < 4; i++) {
                int m = m0 + wm * 32 + fi * 16 + 4 * g + i;
                float v = acc[fi][fj][i];
                if (isq) {
                    qb[(size_t)m * 384 + n] = f2b(v * qscale);
                } else {
                    y2f[(size_t)m * 384 + (n - 384)] = v + sr2_b[n - 384];
                }
            }
        }
    }
}

// ---------- depthwise 3x3x3 SAME residual conv on V (both branches, one launch) ----------
__device__ __forceinline__ void dwconv_one(const ushort_t* __restrict__ vin,
                                           const float* __restrict__ wt,
                                           const float* __restrict__ bias,
                                           ushort_t* __restrict__ vout,
                                           int Hs, int Wsz, int Ds, int S, int gid) {
    int c2 = gid % 192;
    int r = gid / 192;
    int n = r % S;
    int b = r / S;
    int dz = n % Ds, wy = (n / Ds) % Wsz, hx = n / (Wsz * Ds);
    float center = b2f(vin[(size_t)(b * S + n) * 384 + c2]);
    float acc = bias[c2];
    for (int kh = -1; kh <= 1; kh++) {
        int h2 = hx + kh; if (h2 < 0 || h2 >= Hs) continue;
        for (int kw = -1; kw <= 1; kw++) {
            int w2 = wy + kw; if (w2 < 0 || w2 >= Wsz) continue;
            for (int kd = -1; kd <= 1; kd++) {
                int d2 = dz + kd; if (d2 < 0 || d2 >= Ds) continue;
                int nn = (h2 * Wsz + w2) * Ds + d2;
                acc += b2f(vin[(size_t)(b * S + nn) * 384 + c2]) *
                       wt[c2 * 27 + (kh + 1) * 9 + (kw + 1) * 3 + (kd + 1)];
            }
        }
    }
    vout[(size_t)(b * S + n) * 192 + c2] = f2b(center + acc);
}

__global__ void dwconv2_kernel(const ushort_t* __restrict__ v2in, const ushort_t* __restrict__ v1in,
                               const float* __restrict__ w2, const float* __restrict__ b2,
                               const float* __restrict__ w1, const float* __restrict__ b1,
                               ushort_t* __restrict__ vo2, ushort_t* __restrict__ vo1) {
    int gid = blockIdx.x * 256 + threadIdx.x;
    const int T2 = 2 * 4096 * 192;
    const int T1 = 2 * 512 * 192;
    if (gid < T2) dwconv_one(v2in, w2, b2, vo2, 16, 16, 16, 4096, gid);
    else if (gid < T2 + T1) dwconv_one(v1in, w1, b1, vo1, 8, 8, 8, 512, gid - T2);
}

// ---------- transpose vmod [b][S][192] -> vt [b][192][S] (both branches, one launch) ----------
__global__ __launch_bounds__(256) void transpose2_kernel(const ushort_t* __restrict__ src2,
                                                         ushort_t* __restrict__ dst2,
                                                         const ushort_t* __restrict__ src1,
                                                         ushort_t* __restrict__ dst1) {
    __shared__ ushort_t t_lds[64][65];
    int bx = blockIdx.x;
    const ushort_t* src; ushort_t* dst; int S, n0;
    if (bx < 64) { src = src2; dst = dst2; S = 4096; n0 = bx * 64; }
    else         { src = src1; dst = dst1; S = 512;  n0 = (bx - 64) * 64; }
    int c0 = blockIdx.y * 64, b = blockIdx.z;
    int tid = threadIdx.x;
#pragma unroll
    for (int i = 0; i < 16; i++) {
        int idx = tid + i * 256;
        int r = idx >> 6, cc = idx & 63;
        t_lds[r][cc] = src[((size_t)b * S + n0 + r) * 192 + c0 + cc];
    }
    __syncthreads();
#pragma unroll
    for (int i = 0; i < 16; i++) {
        int idx = tid + i * 256;
        int r = idx >> 6, cc = idx & 63;
        dst[((size_t)b * 192 + c0 + r) * S + n0 + cc] = t_lds[cc][r];
    }
}

// ---------- MFMA flash attention v5s (verified plateau config) ----------
__global__ __launch_bounds__(256, 4) void attn_mfma5s(
    const ushort_t* __restrict__ qbuf,
    const ushort_t* __restrict__ kv1,
    const ushort_t* __restrict__ kv2,
    const ushort_t* __restrict__ vt1,
    const ushort_t* __restrict__ vt2,
    ushort_t* __restrict__ obuf)
{
    __shared__ __align__(16) char lds_raw[18432];
    bf16_t (*P)[32][72] = (bf16_t (*)[32][72])lds_raw;
    float (*CF)[64][14] = (float (*)[64][14])lds_raw;

    const int N = 4096;
    int tid = threadIdx.x;
    int q0 = blockIdx.x * 32, hl = 7 - blockIdx.y, b = blockIdx.z;
    int wave = tid >> 6, lane = tid & 63, g = lane >> 4, c = lane & 15;
    int br2 = hl >> 2;
    int NK = br2 ? 4096 : 512;
    const ushort_t* kbuf = br2 ? kv2 : kv1;
    const ushort_t* vtb  = br2 ? vt2 : vt1;
    int hloc = hl & 3;
    int NKc = NK >> 2;
    int kb0 = wave * NKc;
    int nkt = NKc >> 6;

    union { uint4 u; bf16x8 v; } zz; zz.u = uint4{0u, 0u, 0u, 0u};
    const bf16x8 zero8 = zz.v;

    bf16x8 bq0[2], bq1[2];
#pragma unroll
    for (int qg = 0; qg < 2; qg++) {
        const ushort_t* qrowp = qbuf + ((size_t)b * N + q0 + qg * 16 + c) * 384 + hl * 48;
        bq0[qg] = *(const bf16x8*)(qrowp + g * 8);
        bq1[qg] = (g < 2) ? *(const bf16x8*)(qrowp + 32 + g * 8) : zero8;
    }

    f32x4 of[3][2];
#pragma unroll
    for (int dt = 0; dt < 3; dt++)
#pragma unroll
        for (int qg = 0; qg < 2; qg++) of[dt][qg] = f32x4{0.f, 0.f, 0.f, 0.f};
    float l_acc[2] = {0.f, 0.f};

    const ushort_t* kp = kbuf + ((size_t)b * NK + kb0 + c) * 384 + hloc * 48;
    const ushort_t* vp = vtb + ((size_t)b * 192 + hloc * 48 + c) * NK + kb0;

    for (int kt = 0; kt < nkt; kt++) {
        f32x4 sf[4][2];
#pragma unroll
        for (int t = 0; t < 4; t++)
#pragma unroll
            for (int qg = 0; qg < 2; qg++) sf[t][qg] = f32x4{0.f, 0.f, 0.f, 0.f};
        __builtin_amdgcn_s_setprio(1);
#pragma unroll
        for (int t = 0; t < 4; t++) {
            const ushort_t* kr = kp + (size_t)(kt * 64 + 16 * t) * 384;
            bf16x8 ak0 = *(const bf16x8*)(kr + g * 8);
            bf16x8 ak1 = (g < 2) ? *(const bf16x8*)(kr + 32 + g * 8) : zero8;
#pragma unroll
            for (int qg = 0; qg < 2; qg++) {
                sf[t][qg] = __builtin_amdgcn_mfma_f32_16x16x32_bf16(ak0, bq0[qg], sf[t][qg], 0, 0, 0);
                sf[t][qg] = __builtin_amdgcn_mfma_f32_16x16x32_bf16(ak1, bq1[qg], sf[t][qg], 0, 0, 0);
            }
        }
        __builtin_amdgcn_s_setprio(0);

#pragma unroll
        for (int qg = 0; qg < 2; qg++) {
#pragma unroll
            for (int t = 0; t < 4; t++) {
                union { ushort4 v; bf16_t h[4]; } pk;
#pragma unroll
                for (int i = 0; i < 4; i++) {
                    float p = exp2f(sf[t][qg][i]);
                    l_acc[qg] += p;
                    pk.h[i] = (bf16_t)p;
                }
                *(ushort4*)&P[wave][qg * 16 + c][16 * t + 4 * g] = pk.v;
            }
        }

        asm volatile("s_waitcnt lgkmcnt(0)" ::: "memory");

        bf16x8 pb0[2], pb1[2];
#pragma unroll
        for (int qg = 0; qg < 2; qg++) {
            pb0[qg] = *(bf16x8*)&P[wave][qg * 16 + c][g * 8];
            pb1[qg] = *(bf16x8*)&P[wave][qg * 16 + c][32 + g * 8];
        }
        __builtin_amdgcn_s_setprio(1);
#pragma unroll
        for (int dt = 0; dt < 3; dt++) {
            const ushort_t* vr = vp + (size_t)(16 * dt) * NK + kt * 64;
            bf16x8 av0 = *(const bf16x8*)(vr + g * 8);
            bf16x8 av1 = *(const bf16x8*)(vr + 32 + g * 8);
#pragma unroll
            for (int qg = 0; qg < 2; qg++) {
                of[dt][qg] = __builtin_amdgcn_mfma_f32_16x16x32_bf16(av0, pb0[qg], of[dt][qg], 0, 0, 0);
                of[dt][qg] = __builtin_amdgcn_mfma_f32_16x16x32_bf16(av1, pb1[qg], of[dt][qg], 0, 0, 0);
            }
        }
        __builtin_amdgcn_s_setprio(0);
    }

#pragma unroll
    for (int qg = 0; qg < 2; qg++) {
        l_acc[qg] += __shfl_xor(l_acc[qg], 16);
        l_acc[qg] += __shfl_xor(l_acc[qg], 32);
    }

#pragma unroll
    for (int qg = 0; qg < 2; qg++) {
        __syncthreads();
        float* cfp = &CF[wave][lane][0];
#pragma unroll
        for (int dt = 0; dt < 3; dt++)
#pragma unroll
            for (int i = 0; i < 4; i++) cfp[dt * 4 + i] = of[dt][qg][i];
        cfp[12] = l_acc[qg];
        __syncthreads();
        if (wave == 0) {
            float lsum = 0.f;
            float oc[12];
#pragma unroll
            for (int j = 0; j < 12; j++) oc[j] = 0.f;
#pragma unroll
            for (int w = 0; w < 4; w++) {
                lsum += CF[w][lane][12];
#pragma unroll
                for (int j = 0; j < 12; j++) oc[j] += CF[w][lane][j];
            }
            float rl = 1.f / lsum;
            int qrow = q0 + qg * 16 + c;
#pragma unroll
            for (int dt = 0; dt < 3; dt++) {
                union { ushort4 v; bf16_t h[4]; } pk;
#pragma unroll
                for (int i = 0; i < 4; i++) pk.h[i] = (bf16_t)(oc[dt * 4 + i] * rl);
                *(ushort4*)&obuf[((size_t)b * N + qrow) * 384 + hl * 48 + 16 * dt + 4 * g] = pk.v;
            }
        }
    }
}

// ---------- host ----------
extern "C" void kernel_launch(void* const* d_in, const int* in_sizes, int n_in,
                              void* d_out, int out_size, void* d_ws, size_t ws_size,
                              hipStream_t stream) {
    const int B = 2, N = 4096, C = 384, N1 = 512, HID = 1536;
    const float* x      = (const float*)d_in[0];
    const float* ln1_w  = (const float*)d_in[1];
    const float* ln1_b  = (const float*)d_in[2];
    const float* q_w    = (const float*)d_in[3];
    const float* sr1_w  = (const float*)d_in[4];
    const float* sr1_b  = (const float*)d_in[5];
    const float* n1_w   = (const float*)d_in[6];
    const float* n1_b   = (const float*)d_in[7];
    const float* sr2_w  = (const float*)d_in[8];
    const float* sr2_b  = (const float*)d_in[9];
    const float* n2_w   = (const float*)d_in[10];
    const float* n2_b   = (const float*)d_in[11];
    const float* kv1_w  = (const float*)d_in[12];
    const float* kv2_w  = (const float*)d_in[13];
    const float* lc1_w  = (const float*)d_in[14];
    const float* lc1_b  = (const float*)d_in[15];
    const float* lc2_w  = (const float*)d_in[16];
    const float* lc2_b  = (const float*)d_in[17];
    const float* proj_w = (const float*)d_in[18];
    const float* proj_b = (const float*)d_in[19];
    const float* ln2_w  = (const float*)d_in[20];
    const float* ln2_b  = (const float*)d_in[21];
    const float* fc1_w  = (const float*)d_in[22];
    const float* fc1_b  = (const float*)d_in[23];
    const float* fc2_w  = (const float*)d_in[24];
    const float* fc2_b  = (const float*)d_in[25];
    float* out = (float*)d_out;

    char* ws = (char*)d_ws;
    ushort_t* wbase = (ushort_t*)ws;
    ushort_t* wqy2 = wbase;
    ushort_t* wkv1 = wbase + 294912;
    ushort_t* wkv2 = wbase + 442368;
    ushort_t* wproj= wbase + 589824;
    ushort_t* wfc1 = wbase + 737280;
    ushort_t* wfc2 = wbase + 1327104;
    ushort_t* wsr1 = wbase + 1916928;
    ushort_t* xa_bf = (ushort_t*)(ws + 6193152);
    ushort_t* qbB   = (ushort_t*)(ws + 12484608);
    ushort_t* x2_bf = (ushort_t*)(ws + 18776064);
    ushort_t* kv2   = (ushort_t*)(ws + 25067520);
    ushort_t* vmod2 = (ushort_t*)(ws + 31358976);
    ushort_t* kv1   = (ushort_t*)(ws + 34504704);
    ushort_t* vmod1 = (ushort_t*)(ws + 35291136);
    ushort_t* x1_bf = (ushort_t*)(ws + 35684352);
    float*    y2f   = (float*)(ws + 36470784);
    ushort_t* A1    = (ushort_t*)(ws + 50626560);
    ushort_t* hid   = (ushort_t*)(ws + 56918016);
    ushort_t* vt2   = (ushort_t*)(ws + 82083840);
    ushort_t* vt1   = (ushort_t*)(ws + 85229568);
    float*    y1p   = (float*)(ws + 85622784);
    ushort_t* Obuf  = xa_bf;
    float*    xres  = y2f;
    ushort_t* xm_bf = A1;

    const float QSCALE = 0.14433756729740643f * 1.4426950408889634f;

    // 0. weights
    prep_weights<<<(3096576 + 255) / 256, 256, 0, stream>>>(q_w, sr2_w, kv1_w, kv2_w,
                                                            proj_w, fc1_w, fc2_w, sr1_w, wbase);
    // 1. xa = LN(x) -> bf16
    ln_kernel<<<B * N, 128, 0, stream>>>(x, ln1_w, ln1_b, nullptr, xa_bf, 0);
    // 2+3. fused q|y2
    gemm_qy2<<<dim3(12, 128), 256, 0, stream>>>(xa_bf, wqy2, sr2_b, qbB, y2f, B * N, QSCALE);
    // 4. x2 = gelu(LN(y2)) -> bf16
    ln_kernel<<<B * N, 128, 0, stream>>>(y2f, n2_w, n2_b, nullptr, x2_bf, 1);
    // 5. im2col + split-K sr1 GEMM
    im2col_kernel<<<(1024 * 3072 + 255) / 256, 256, 0, stream>>>(xa_bf, A1);
    gemm64sk<<<dim3(6, 16, 4), 256, 0, stream>>>(A1, wsr1, y1p);
    // 6. x1 = gelu(LN(sum partials + sr1_b)) -> bf16
    ln4_kernel<<<B * N1, 128, 0, stream>>>(y1p, sr1_b, n1_w, n1_b, x1_bf);
    // 7+8. merged kv projections (bf16)
    gemm_kv<<<dim3(6, 144), 256, 0, stream>>>(x2_bf, wkv2, kv2, x1_bf, wkv1, kv1);
    // 9/10. vmod = v + dwconv3(v) [one launch], then transpose -> vt [one launch]
    {
        const int T2 = B * N * 192, T1 = B * N1 * 192;
        dwconv2_kernel<<<(T2 + T1 + 255) / 256, 256, 0, stream>>>(kv2 + 192, kv1 + 192,
                                                                  lc2_w, lc2_b, lc1_w, lc1_b,
                                                                  vmod2, vmod1);
        transpose2_kernel<<<dim3(72, 3, 2), 256, 0, stream>>>(vmod2, vt2, vmod1, vt1);
    }
    // 11. attention v5s
    attn_mfma5s<<<dim3(N / 32, 8, B), 256, 0, stream>>>(qbB, kv1, kv2, vt1, vt2, Obuf);
    // 13. xres = x + O @ proj_w^T + proj_b (f32)
    gemm64<<<dim3(6, 128), 256, 0, stream>>>(Obuf, wproj, proj_b, x,
                                             xres, nullptr, B * N, C, C, 0, 1.f);
    // 14. xm = LN(xres) -> bf16
    ln_kernel<<<B * N, 128, 0, stream>>>(xres, ln2_w, ln2_b, nullptr, xm_bf, 0);
    // 15. hid = gelu(xm @ fc1^T + b) (bf16)
    mfma_gemm<<<dim3(12, 64), 256, 0, stream>>>(xm_bf, wfc1, fc1_b, nullptr,
                                                nullptr, hid, B * N, HID, C, 1);
    // 16. out = xres + hid @ fc2^T + b (f32 -> d_out)
    gemm64<<<dim3(6, 128), 256, 0, stream>>>(hid, wfc2, fc2_b, xres,
                                             out, nullptr, B * N, C, HID, 0, 1.f);
}